// Round 8
// baseline (487.097 us; speedup 1.0000x reference)
//
#include <hip/hip_runtime.h>
#include <hip/hip_bf16.h>
#include <hip/hip_fp16.h>

#define EPS 1e-8f
#define PI_F 3.14159265358979323846f

typedef _Float16 half8 __attribute__((ext_vector_type(8)));
typedef float f32x4 __attribute__((ext_vector_type(4)));
typedef float f32x2 __attribute__((ext_vector_type(2)));

#define NBLK 512u

__device__ __forceinline__ float gelu_exact(float v) {
    return 0.5f * v * (1.0f + erff(v * 0.70710678118654752f));
}

// Manual grid barrier (cooperative launch silently failed in R7's harness).
// Counters pre-zeroed by hipMemsetAsync each call. Agent-scope release fence
// before arrival (wbL2) + agent acquire fence after the spin (invL1/L2) give
// cross-XCD visibility of plain stores. Spin bound = visible failure, not hang.
__device__ __forceinline__ void grid_barrier(unsigned* ctr) {
    __syncthreads();
    if (threadIdx.x == 0) {
        __threadfence();
        __hip_atomic_fetch_add(ctr, 1u, __ATOMIC_RELEASE, __HIP_MEMORY_SCOPE_AGENT);
        long spins = 0;
        while (__hip_atomic_load(ctr, __ATOMIC_ACQUIRE, __HIP_MEMORY_SCOPE_AGENT) < NBLK) {
            __builtin_amdgcn_s_sleep(2);
            if (++spins > (long)50000000) break;   // failsafe; never fires when co-resident
        }
        __threadfence();
    }
    __syncthreads();
}

// ---------------------------------------------------------------------------
// ONE kernel, 512 blocks x 256 threads. Occupancy margin: LDS 32 KB (<=5
// blocks/CU), launch_bounds(256,2) (VGPR<=256 -> >=2 blocks/CU) => all 512
// co-resident (2/CU). Phases separated by manual grid barriers:
//  P0: embed_w -> permuted transposed fp16 hi/lo Wth/Wtl [512 j][256 k]
//  P1: embed GEMM (R4-proven staging/swizzle + R6-proven 2x2 wave tiling,
//      3-pass fp16 split) + polar -> XY8 fp8 + mean partial slots (no atomics)
//  P2: 8-layer mean recurrence -> DX,DY
//  P3: pool partials    P4: classifier -> out
// ---------------------------------------------------------------------------
__global__ __launch_bounds__(256, 2) void fused_all(
    const float* __restrict__ x, const float* __restrict__ embed_w,
    const float* __restrict__ embed_b,
    const float* __restrict__ mw1, const float* __restrict__ mb1,
    const float* __restrict__ mw2, const float* __restrict__ mb2,
    const float* __restrict__ pw1, const float* __restrict__ pb1,
    const float* __restrict__ pw2, const float* __restrict__ pb2,
    const float* __restrict__ cw1, const float* __restrict__ cb1,
    const float* __restrict__ cw2, const float* __restrict__ cb2,
    float* __restrict__ out,
    unsigned short* __restrict__ XY8,
    _Float16* __restrict__ Wth, _Float16* __restrict__ Wtl,
    float* __restrict__ XMpart, float* __restrict__ YMpart,
    float* __restrict__ PoolPart,
    float* __restrict__ DX, float* __restrict__ DY,
    unsigned* __restrict__ bar)
{
    __shared__ __attribute__((aligned(16))) char smem[32768];
    const int tid = threadIdx.x;
    const int bid = blockIdx.x;          // 0..511

    // ================= Phase 0: weight convert (131072 elements exact) ====
    {
        int idx = bid * 256 + tid;
        int col = idx & 511, k = idx >> 9;
        int d = col & 255, g = d >> 6;
        int j = g * 128 + ((col < 256) ? (d & 63) : (64 + (d & 63)));
        float f = embed_w[k * 512 + col];
        _Float16 h = (_Float16)f;
        Wth[j * 256 + k] = h;
        Wtl[j * 256 + k] = (_Float16)(f - (float)h);
    }
    grid_barrier(bar + 0);

    // ================= Phase 1: GEMM + polar (R4 structure, g-loop) =======
    {
        _Float16* Ah = (_Float16*)smem;      // [128][32]
        _Float16* Al = Ah + 4096;
        _Float16* Bh = Al + 4096;
        _Float16* Bl = Bh + 4096;            // 32 KB total
        const int wave = tid >> 6, lane = tid & 63;
        const int q = lane >> 4, ln = lane & 15;
        const int mh = wave & 1, a2 = wave >> 1;    // 2x2 tiling (R6-verified)
        const int m0 = bid * 128;
        const int b  = bid >> 3, sub = bid & 7;

        for (int g = 0; g < 4; ++g) {
            f32x4 acc[4][4];
#pragma unroll
            for (int mi = 0; mi < 4; ++mi)
#pragma unroll
                for (int t = 0; t < 4; ++t)
                    acc[mi][t] = (f32x4){0.f, 0.f, 0.f, 0.f};

            for (int kt = 0; kt < 8; ++kt) {
                __syncthreads();
                // ---- stage B [128 n][32 k] hi/lo (R4-verbatim) ----
#pragma unroll
                for (int c2 = 0; c2 < 2; ++c2) {
                    int idx = c2 * 256 + tid;
                    int r = idx >> 2, c = idx & 3;
                    size_t go = (size_t)(g * 128 + r) * 256 + kt * 32 + c * 8;
                    half8 vh = *(const half8*)(Wth + go);
                    half8 vl = *(const half8*)(Wtl + go);
                    int pos = c ^ ((r >> 1) & 3);
                    *(half8*)&Bh[r * 32 + pos * 8] = vh;
                    *(half8*)&Bl[r * 32 + pos * 8] = vl;
                }
                // ---- stage A [128 m][32 k] fp32 -> fp16 hi/lo (R4-verbatim)
#pragma unroll
                for (int L = 0; L < 2; ++L) {
                    int idx = L * 256 + tid;
                    int r = idx >> 2, cq = idx & 3;
                    const float* src = x + (size_t)(m0 + r) * 256 + kt * 32 + cq * 8;
                    const float4 f0 = *(const float4*)(src);
                    const float4 f1 = *(const float4*)(src + 4);
                    half8 hh, ll;
                    hh[0] = (_Float16)f0.x; ll[0] = (_Float16)(f0.x - (float)hh[0]);
                    hh[1] = (_Float16)f0.y; ll[1] = (_Float16)(f0.y - (float)hh[1]);
                    hh[2] = (_Float16)f0.z; ll[2] = (_Float16)(f0.z - (float)hh[2]);
                    hh[3] = (_Float16)f0.w; ll[3] = (_Float16)(f0.w - (float)hh[3]);
                    hh[4] = (_Float16)f1.x; ll[4] = (_Float16)(f1.x - (float)hh[4]);
                    hh[5] = (_Float16)f1.y; ll[5] = (_Float16)(f1.y - (float)hh[5]);
                    hh[6] = (_Float16)f1.z; ll[6] = (_Float16)(f1.z - (float)hh[6]);
                    hh[7] = (_Float16)f1.w; ll[7] = (_Float16)(f1.w - (float)hh[7]);
                    int pos = cq ^ ((r >> 1) & 3);
                    *(half8*)&Ah[r * 32 + pos * 8] = hh;
                    *(half8*)&Al[r * 32 + pos * 8] = ll;
                }
                __syncthreads();

                // ---- fragments ----
                half8 bh[4], bl[4], ah[4], al[4];
#pragma unroll
                for (int t = 0; t < 4; ++t) {
                    int grp = 2 * a2 + (t & 1) + ((t >> 1) << 2); // 2a2,2a2+1,2a2+4,2a2+5
                    int rn  = grp * 16 + ln;
                    int off = rn * 32 + (q ^ ((rn >> 1) & 3)) * 8;
                    bh[t] = *(const half8*)&Bh[off];
                    bl[t] = *(const half8*)&Bl[off];
                }
#pragma unroll
                for (int mi = 0; mi < 4; ++mi) {
                    int row = mh * 64 + mi * 16 + ln;
                    int off = row * 32 + (q ^ ((row >> 1) & 3)) * 8;
                    ah[mi] = *(const half8*)&Ah[off];
                    al[mi] = *(const half8*)&Al[off];
                }
                // ---- 3 passes (R2: all 3 needed), 16 indep chains each ----
#pragma unroll
                for (int mi = 0; mi < 4; ++mi)
#pragma unroll
                    for (int t = 0; t < 4; ++t)
                        acc[mi][t] = __builtin_amdgcn_mfma_f32_16x16x32_f16(ah[mi], bh[t], acc[mi][t], 0, 0, 0);
#pragma unroll
                for (int mi = 0; mi < 4; ++mi)
#pragma unroll
                    for (int t = 0; t < 4; ++t)
                        acc[mi][t] = __builtin_amdgcn_mfma_f32_16x16x32_f16(ah[mi], bl[t], acc[mi][t], 0, 0, 0);
#pragma unroll
                for (int mi = 0; mi < 4; ++mi)
#pragma unroll
                    for (int t = 0; t < 4; ++t)
                        acc[mi][t] = __builtin_amdgcn_mfma_f32_16x16x32_f16(al[mi], bh[t], acc[mi][t], 0, 0, 0);
            }

            // ---- epilogue (R6-verified): t01 pairs r-group with theta ----
            // C/D: col = lane&15, row = (lane>>4)*4 + reg  [m89]
#pragma unroll
            for (int t01 = 0; t01 < 2; ++t01) {
                const int d  = g * 64 + (2 * a2 + t01) * 16 + ln;
                const float b1 = embed_b[d];
                const float b2 = embed_b[256 + d];
                float sx = 0.f, sy = 0.f;
#pragma unroll
                for (int mi = 0; mi < 4; ++mi) {
#pragma unroll
                    for (int i = 0; i < 4; ++i) {
                        const int row = m0 + mh * 64 + mi * 16 + q * 4 + i;
                        const float h1 = acc[mi][t01][i] + b1;
                        const float h2 = acc[mi][t01 + 2][i] + b2;
                        const float rr = fabsf(h1) + 0.1f;
                        float sv, cv;
                        __sincosf(PI_F * h2, &sv, &cv);
                        const float xc = rr * cv, yc = rr * sv;
                        int pk = __builtin_amdgcn_cvt_pk_fp8_f32(xc, yc, 0, false);
                        XY8[(size_t)row * 256 + d] = (unsigned short)pk;
                        sx += xc; sy += yc;   // mean path stays fp32
                    }
                }
                sx += __shfl_down(sx, 32); sx += __shfl_down(sx, 16);
                sy += __shfl_down(sy, 32); sy += __shfl_down(sy, 16);
                if (lane < 16) {   // slot (sub,mh) unique per writer -> plain store
                    XMpart[(sub * 2 + mh) * 16384 + b * 256 + d] = sx;
                    YMpart[(sub * 2 + mh) * 16384 + b * 256 + d] = sy;
                }
            }
        }
    }
    grid_barrier(bar + 16);

    // ================= Phase 2: layer recurrence on means ================
    {
        float* s_mw1 = (float*)smem;
        float* s_mb1 = s_mw1 + 256;
        float* s_mw2 = s_mb1 + 256;
        float* s_pb1 = s_mw2 + 256;
        float* s_pw1 = s_pb1 + 256;          // 512
        float* s_pw2 = s_pw1 + 512;          // 512
        float* s_mb2 = s_pw2 + 512;          // 8
        float* s_pb2 = s_mb2 + 8;            // 16
        s_mw1[tid] = mw1[tid]; s_mb1[tid] = mb1[tid];
        s_mw2[tid] = mw2[tid]; s_pb1[tid] = pb1[tid];
        s_pw1[tid] = pw1[tid]; s_pw1[256 + tid] = pw1[256 + tid];
        s_pw2[tid] = pw2[tid]; s_pw2[256 + tid] = pw2[256 + tid];
        if (tid < 8)  s_mb2[tid] = mb2[tid];
        if (tid < 16) s_pb2[tid] = pb2[tid];
        __syncthreads();

        const int gid = bid * 256 + tid;
        const int idx = gid >> 3;            // (b,d), 16384
        const int subk = gid & 7;            // k-eighth
        float xm = 0.f, ym = 0.f;
#pragma unroll
        for (int s = 0; s < 16; ++s) {
            xm += XMpart[s * 16384 + idx];
            ym += YMpart[s * 16384 + idx];
        }
        xm *= (1.0f / 1024.0f); ym *= (1.0f / 1024.0f);
        float dxa = 0.f, dya = 0.f;
#pragma unroll 1
        for (int i = 0; i < 8; ++i) {
            float r2    = xm * xm + ym * ym;
            float r_agg = sqrtf(r2 + EPS);
            float hyp   = sqrtf(r2);
            float inv   = hyp > 0.f ? 1.0f / hyp : 0.f;
            float st    = ym * inv;
            float ct    = hyp > 0.f ? xm * inv : 1.0f;
            float log_r = logf(r_agg + EPS);
            float lr = 0.f, p0 = 0.f, p1 = 0.f;
#pragma unroll
            for (int k4 = 0; k4 < 4; ++k4) {
                int k = subk * 4 + k4;
                float hm = gelu_exact(log_r * s_mw1[i * 32 + k] + s_mb1[i * 32 + k]);
                lr += hm * s_mw2[i * 32 + k];
                float hp = gelu_exact(st * s_pw1[i * 64 + k] + ct * s_pw1[i * 64 + 32 + k] + s_pb1[i * 32 + k]);
                p0 += hp * s_pw2[i * 64 + 2 * k + 0];
                p1 += hp * s_pw2[i * 64 + 2 * k + 1];
            }
            lr += __shfl_xor(lr, 1); lr += __shfl_xor(lr, 2); lr += __shfl_xor(lr, 4);
            p0 += __shfl_xor(p0, 1); p0 += __shfl_xor(p0, 2); p0 += __shfl_xor(p0, 4);
            p1 += __shfl_xor(p1, 1); p1 += __shfl_xor(p1, 2); p1 += __shfl_xor(p1, 4);
            lr += s_mb2[i];
            p0 += s_pb2[i * 2 + 0];
            p1 += s_pb2[i * 2 + 1];
            float r_trans = expf(lr);
            float hp2  = sqrtf(p0 * p0 + p1 * p1);
            float invp = hp2 > 0.f ? 1.0f / hp2 : 0.f;
            float ctt  = hp2 > 0.f ? p1 * invp : 1.0f;
            float stt  = p0 * invp;
            float dx = r_trans * ctt;
            float dy = r_trans * stt;
            dxa += dx; dya += dy; xm += dx; ym += dy;
        }
        if (subk == 0) { DX[idx] = dxa; DY[idx] = dya; }
    }
    grid_barrier(bar + 32);

    // ================= Phase 3: pool partials ============================
    {
        float (*red)[9] = (float(*)[9])smem;
        const int b = bid >> 3, sc = bid & 7;
        const int dg = tid & 31;
        const int sh = tid >> 5;
        const int d0 = dg * 8;
        float dxv[8], dyv[8], s[8];
#pragma unroll
        for (int j = 0; j < 8; ++j) {
            dxv[j] = DX[b * 256 + d0 + j];
            dyv[j] = DY[b * 256 + d0 + j];
            s[j] = 0.f;
        }
        const int r0 = sc * 128 + sh * 16;
        const size_t base = ((size_t)b * 1024 + r0) * 256 + d0;
#pragma unroll 4
        for (int i = 0; i < 16; ++i) {
            const int4 v = *(const int4*)(XY8 + base + (size_t)i * 256);
            const int wv[4] = {v.x, v.y, v.z, v.w};
#pragma unroll
            for (int w = 0; w < 4; ++w) {
                f32x2 pa = __builtin_amdgcn_cvt_pk_f32_fp8(wv[w], false);
                f32x2 pb = __builtin_amdgcn_cvt_pk_f32_fp8(wv[w], true);
                float xa = pa[0] + dxv[2 * w],     ya = pa[1] + dyv[2 * w];
                float xb = pb[0] + dxv[2 * w + 1], yb = pb[1] + dyv[2 * w + 1];
                s[2 * w]     += sqrtf(xa * xa + ya * ya + EPS);
                s[2 * w + 1] += sqrtf(xb * xb + yb * yb + EPS);
            }
        }
#pragma unroll
        for (int j = 0; j < 8; ++j) red[tid][j] = s[j];
        __syncthreads();
        if (tid < 32) {
#pragma unroll
            for (int j = 0; j < 8; ++j) {
                float t = 0.f;
#pragma unroll
                for (int c = 0; c < 8; ++c) t += red[c * 32 + tid][j];
                PoolPart[sc * 16384 + b * 256 + tid * 8 + j] = t;  // plain store
            }
        }
    }
    grid_barrier(bar + 48);

    // ================= Phase 4: classifier (blocks 0..63) ================
    if (bid < 64) {
        float* pl = (float*)smem;
        float (*part)[32] = (float(*)[32])(pl + 256);
        float* hd = (float*)((float*)part + 256);
        const int b = bid;
        float ps = 0.f;
#pragma unroll
        for (int sc = 0; sc < 8; ++sc) ps += PoolPart[sc * 16384 + b * 256 + tid];
        pl[tid] = ps * (1.0f / 1024.0f);
        __syncthreads();
        const int hu = tid & 31, kc = tid >> 5;
        float a = 0.f;
        for (int k = kc * 32; k < kc * 32 + 32; ++k) a += pl[k] * cw1[k * 32 + hu];
        part[kc][hu] = a;
        __syncthreads();
        if (tid < 32) {
            float s = cb1[tid];
#pragma unroll
            for (int c = 0; c < 8; ++c) s += part[c][tid];
            hd[tid] = gelu_exact(s);
        }
        __syncthreads();
        for (int n = tid; n < 1000; n += 256) {
            float s = cb2[n];
#pragma unroll
            for (int k = 0; k < 32; ++k) s += hd[k] * cw2[k * 1000 + n];
            out[b * 1000 + n] = s;
        }
    }
}

// ---------------------------------------------------------------------------
extern "C" void kernel_launch(void* const* d_in, const int* in_sizes, int n_in,
                              void* d_out, int out_size, void* d_ws, size_t ws_size,
                              hipStream_t stream)
{
    const float* x       = (const float*)d_in[0];
    const float* embed_w = (const float*)d_in[1];
    const float* embed_b = (const float*)d_in[2];
    const float* mag_w1  = (const float*)d_in[3];
    const float* mag_b1  = (const float*)d_in[4];
    const float* mag_w2  = (const float*)d_in[5];
    const float* mag_b2  = (const float*)d_in[6];
    const float* ph_w1   = (const float*)d_in[7];
    const float* ph_b1   = (const float*)d_in[8];
    const float* ph_w2   = (const float*)d_in[9];
    const float* ph_b2   = (const float*)d_in[10];
    const float* cls_w1  = (const float*)d_in[11];
    const float* cls_b1  = (const float*)d_in[12];
    const float* cls_w2  = (const float*)d_in[13];
    const float* cls_b2  = (const float*)d_in[14];
    float* out = (float*)d_out;

    char* ws = (char*)d_ws;
    unsigned short* XY8 = (unsigned short*)(ws + 0);   // 33554432 B
    _Float16* Wth  = (_Float16*)(ws + 33554432);       // 262144
    _Float16* Wtl  = (_Float16*)(ws + 33816576);       // 262144
    float* XMpart  = (float*)(ws + 34078720);          // 1048576
    float* YMpart  = (float*)(ws + 35127296);          // 1048576
    float* PoolPart= (float*)(ws + 36175872);          // 524288
    float* DX      = (float*)(ws + 36700160);          // 65536
    float* DY      = (float*)(ws + 36765696);          // 65536
    unsigned* bar  = (unsigned*)(ws + 36831232);       // 4 counters, 64B apart

    hipMemsetAsync(ws + 36831232, 0, 256, stream);     // zero barrier counters

    fused_all<<<512, 256, 0, stream>>>(
        x, embed_w, embed_b,
        mag_w1, mag_b1, mag_w2, mag_b2,
        ph_w1, ph_b1, ph_w2, ph_b2,
        cls_w1, cls_b1, cls_w2, cls_b2,
        out, XY8, Wth, Wtl, XMpart, YMpart, PoolPart, DX, DY, bar);
}

// Round 9
// 279.471 us; speedup vs baseline: 1.7429x; 1.7429x over previous
//
#include <hip/hip_runtime.h>
#include <hip/hip_bf16.h>
#include <hip/hip_fp16.h>

#define EPS 1e-8f
#define PI_F 3.14159265358979323846f

typedef _Float16 half8 __attribute__((ext_vector_type(8)));
typedef float f32x4 __attribute__((ext_vector_type(4)));
typedef float f32x2 __attribute__((ext_vector_type(2)));

__device__ __forceinline__ float gelu_exact(float v) {
    return 0.5f * v * (1.0f + erff(v * 0.70710678118654752f));
}

// ---------------------------------------------------------------------------
// Kernel 0 (R4-verbatim + wider zero): embed_w -> permuted transposed fp16
// hi/lo Wth/Wtl [512 j][256 k]; zero-inits XMsum/YMsum/pooled/cnt.
// ---------------------------------------------------------------------------
__global__ void convertW(const float* __restrict__ W,
                         _Float16* __restrict__ Wth, _Float16* __restrict__ Wtl,
                         float* __restrict__ zero_base) {
    int idx = blockIdx.x * 256 + threadIdx.x;   // 0..131071
    if (idx < 49216) zero_base[idx] = 0.f;      // XMsum,YMsum,pooled,cnt(64u)
    int col = idx & 511, k = idx >> 9;
    int d = col & 255, g = d >> 6;
    int j = g * 128 + ((col < 256) ? (d & 63) : (64 + (d & 63)));
    float f = W[k * 512 + col];
    _Float16 h = (_Float16)f;
    Wth[j * 256 + k] = h;
    Wtl[j * 256 + k] = (_Float16)(f - (float)h);
}

// ---------------------------------------------------------------------------
// Kernel 1 (R4-VERBATIM, best measured: 77us, FETCH 36MB): embed GEMM,
// 3-pass fp16 split, fused polar, XCD swizzle, fp8 XY8 store, mean atomics.
// ---------------------------------------------------------------------------
__global__ __launch_bounds__(256, 4) void gemm_embed(
    const float* __restrict__ x,
    const _Float16* __restrict__ Wth, const _Float16* __restrict__ Wtl,
    const float* __restrict__ bias,
    unsigned short* __restrict__ XY8,
    float* __restrict__ XMsum, float* __restrict__ YMsum)
{
    __shared__ __attribute__((aligned(16))) _Float16 Ah[4096], Al[4096], Bh[4096], Bl[4096];
    const int tid  = threadIdx.x;
    const int wave = tid >> 6;
    const int lane = tid & 63;
    const int id   = blockIdx.x;
    const int xcd  = id & 7;
    const int s    = id >> 3;
    const int g    = s & 3;                  // d-range [64g, 64g+64)
    const int mt   = (s >> 2) * 8 + xcd;     // 0..511
    const int m0   = mt * 128;
    const int q    = lane >> 4, ln = lane & 15;

    f32x4 acc[8][2];
#pragma unroll
    for (int mi = 0; mi < 8; ++mi) {
        acc[mi][0] = (f32x4){0.f, 0.f, 0.f, 0.f};
        acc[mi][1] = (f32x4){0.f, 0.f, 0.f, 0.f};
    }

    for (int kt = 0; kt < 8; ++kt) {
        __syncthreads();
        // ---- stage B tiles [128 n][32 k] hi/lo ----
#pragma unroll
        for (int c2 = 0; c2 < 2; ++c2) {
            int idx = c2 * 256 + tid;
            int r = idx >> 2, c = idx & 3;
            size_t go = (size_t)(g * 128 + r) * 256 + kt * 32 + c * 8;
            half8 vh = *(const half8*)(Wth + go);
            half8 vl = *(const half8*)(Wtl + go);
            int pos = c ^ ((r >> 1) & 3);
            *(half8*)&Bh[r * 32 + pos * 8] = vh;
            *(half8*)&Bl[r * 32 + pos * 8] = vl;
        }
        // ---- stage A tile [128 m][32 k]: fp32 -> fp16 hi + lo residual ----
#pragma unroll
        for (int L = 0; L < 2; ++L) {
            int idx = L * 256 + tid;
            int r = idx >> 2, cq = idx & 3;
            const float* src = x + (size_t)(m0 + r) * 256 + kt * 32 + cq * 8;
            const float4 f0 = *(const float4*)(src);
            const float4 f1 = *(const float4*)(src + 4);
            half8 hh, ll;
            hh[0] = (_Float16)f0.x; ll[0] = (_Float16)(f0.x - (float)hh[0]);
            hh[1] = (_Float16)f0.y; ll[1] = (_Float16)(f0.y - (float)hh[1]);
            hh[2] = (_Float16)f0.z; ll[2] = (_Float16)(f0.z - (float)hh[2]);
            hh[3] = (_Float16)f0.w; ll[3] = (_Float16)(f0.w - (float)hh[3]);
            hh[4] = (_Float16)f1.x; ll[4] = (_Float16)(f1.x - (float)hh[4]);
            hh[5] = (_Float16)f1.y; ll[5] = (_Float16)(f1.y - (float)hh[5]);
            hh[6] = (_Float16)f1.z; ll[6] = (_Float16)(f1.z - (float)hh[6]);
            hh[7] = (_Float16)f1.w; ll[7] = (_Float16)(f1.w - (float)hh[7]);
            int pos = cq ^ ((r >> 1) & 3);
            *(half8*)&Ah[r * 32 + pos * 8] = hh;
            *(half8*)&Al[r * 32 + pos * 8] = ll;
        }
        __syncthreads();

        // ---- fragments ----
        half8 bh[2], bl[2], am[8];
#pragma unroll
        for (int t = 0; t < 2; ++t) {
            int rn = (t * 4 + wave) * 16 + ln;
            int off = rn * 32 + (q ^ ((rn >> 1) & 3)) * 8;
            bh[t] = *(const half8*)&Bh[off];
            bl[t] = *(const half8*)&Bl[off];
        }
#pragma unroll
        for (int mi = 0; mi < 8; ++mi) {
            int row = mi * 16 + ln;
            am[mi] = *(const half8*)&Ah[row * 32 + (q ^ ((row >> 1) & 3)) * 8];
        }
#pragma unroll
        for (int mi = 0; mi < 8; ++mi)
#pragma unroll
            for (int t = 0; t < 2; ++t)
                acc[mi][t] = __builtin_amdgcn_mfma_f32_16x16x32_f16(am[mi], bh[t], acc[mi][t], 0, 0, 0);
#pragma unroll
        for (int mi = 0; mi < 8; ++mi)
#pragma unroll
            for (int t = 0; t < 2; ++t)
                acc[mi][t] = __builtin_amdgcn_mfma_f32_16x16x32_f16(am[mi], bl[t], acc[mi][t], 0, 0, 0);
#pragma unroll
        for (int mi = 0; mi < 8; ++mi) {
            int row = mi * 16 + ln;
            half8 alv = *(const half8*)&Al[row * 32 + (q ^ ((row >> 1) & 3)) * 8];
#pragma unroll
            for (int t = 0; t < 2; ++t)
                acc[mi][t] = __builtin_amdgcn_mfma_f32_16x16x32_f16(alv, bh[t], acc[mi][t], 0, 0, 0);
        }
    }

    // ---- epilogue: wave owns d = g*64 + wave*16 + ln for all 128 rows ----
    // C/D layout: col = lane&15, row = (lane>>4)*4 + reg  [m89 verified]
    const int d  = g * 64 + wave * 16 + ln;
    const int b  = m0 >> 10;
    const float b1 = bias[d];
    const float b2 = bias[256 + d];
    float sx = 0.f, sy = 0.f;
#pragma unroll
    for (int mi = 0; mi < 8; ++mi) {
#pragma unroll
        for (int i = 0; i < 4; ++i) {
            const int row = m0 + mi * 16 + q * 4 + i;
            const float h1 = acc[mi][0][i] + b1;
            const float h2 = acc[mi][1][i] + b2;
            const float rr = fabsf(h1) + 0.1f;
            float sv, cv;
            __sincosf(PI_F * h2, &sv, &cv);
            const float xc = rr * cv, yc = rr * sv;
            int pk = __builtin_amdgcn_cvt_pk_fp8_f32(xc, yc, 0, false);
            XY8[(size_t)row * 256 + d] = (unsigned short)pk;
            sx += xc; sy += yc;    // mean path stays full fp32
        }
    }
    sx += __shfl_down(sx, 32); sx += __shfl_down(sx, 16);
    sy += __shfl_down(sy, 32); sy += __shfl_down(sy, 16);
    if (lane < 16) {
        atomicAdd(&XMsum[b * 256 + d], sx);
        atomicAdd(&YMsum[b * 256 + d], sy);
    }
}

// ---------------------------------------------------------------------------
// Kernel 2: fused tail. 512 blocks = (b = bid>>3, sc = bid&7).
//  A) layer recurrence for batch b, recomputed per block (8x redundant,
//     thread d = tid, serial k=32) -> sdx/sdy in LDS
//  B) pool this block's s-chunk (fp8 16B loads), LDS reduce, atomicAdd pooled
//  C) last block per b (device-scope counter + fences) runs the classifier
// ---------------------------------------------------------------------------
__global__ __launch_bounds__(256) void tail_kernel(
    const unsigned short* __restrict__ XY8,
    const float* __restrict__ XMsum, const float* __restrict__ YMsum,
    const float* __restrict__ mw1, const float* __restrict__ mb1,
    const float* __restrict__ mw2, const float* __restrict__ mb2,
    const float* __restrict__ pw1, const float* __restrict__ pb1,
    const float* __restrict__ pw2, const float* __restrict__ pb2,
    const float* __restrict__ cw1, const float* __restrict__ cb1,
    const float* __restrict__ cw2, const float* __restrict__ cb2,
    float* __restrict__ pooled, unsigned* __restrict__ cnt,
    float* __restrict__ out)
{
    __shared__ float s_mw1[256], s_mb1[256], s_mw2[256], s_mb2[8];
    __shared__ float s_pw1[512], s_pb1[256], s_pw2[512], s_pb2[16];
    __shared__ float sdx[256], sdy[256];
    __shared__ float red[256][9];
    __shared__ float pl[256], part[8][32], hd[32];
    __shared__ int last_flag;
    const int tid = threadIdx.x;
    const int bid = blockIdx.x;
    const int b = bid >> 3, sc = bid & 7;

    // ---- load MLP weights ----
    s_mw1[tid] = mw1[tid]; s_mb1[tid] = mb1[tid];
    s_mw2[tid] = mw2[tid]; s_pb1[tid] = pb1[tid];
    s_pw1[tid] = pw1[tid]; s_pw1[256 + tid] = pw1[256 + tid];
    s_pw2[tid] = pw2[tid]; s_pw2[256 + tid] = pw2[256 + tid];
    if (tid < 8)  s_mb2[tid] = mb2[tid];
    if (tid < 16) s_pb2[tid] = pb2[tid];
    __syncthreads();

    // ---- A) layer recurrence, thread d = tid ----
    {
        const int idx = b * 256 + tid;
        float xm = XMsum[idx] * (1.0f / 1024.0f);
        float ym = YMsum[idx] * (1.0f / 1024.0f);
        float dxa = 0.f, dya = 0.f;
#pragma unroll 1
        for (int i = 0; i < 8; ++i) {
            float r2    = xm * xm + ym * ym;
            float r_agg = sqrtf(r2 + EPS);
            float hyp   = sqrtf(r2);
            float inv   = hyp > 0.f ? 1.0f / hyp : 0.f;
            float st    = ym * inv;
            float ct    = hyp > 0.f ? xm * inv : 1.0f;
            float log_r = logf(r_agg + EPS);
            float lr = s_mb2[i];
            float p0 = s_pb2[i * 2 + 0], p1 = s_pb2[i * 2 + 1];
#pragma unroll 4
            for (int k = 0; k < 32; ++k) {
                float hm = gelu_exact(log_r * s_mw1[i * 32 + k] + s_mb1[i * 32 + k]);
                lr += hm * s_mw2[i * 32 + k];
                float hp = gelu_exact(st * s_pw1[i * 64 + k] + ct * s_pw1[i * 64 + 32 + k] + s_pb1[i * 32 + k]);
                p0 += hp * s_pw2[i * 64 + 2 * k + 0];
                p1 += hp * s_pw2[i * 64 + 2 * k + 1];
            }
            float r_trans = expf(lr);
            float hp2  = sqrtf(p0 * p0 + p1 * p1);
            float invp = hp2 > 0.f ? 1.0f / hp2 : 0.f;
            float ctt  = hp2 > 0.f ? p1 * invp : 1.0f;
            float stt  = p0 * invp;
            float dx = r_trans * ctt;
            float dy = r_trans * stt;
            dxa += dx; dya += dy; xm += dx; ym += dy;
        }
        sdx[tid] = dxa; sdy[tid] = dya;
    }
    __syncthreads();

    // ---- B) pool this s-chunk (R4 pool structure, DX/DY from LDS) ----
    {
        const int dg = tid & 31;           // d = dg*8 .. dg*8+7
        const int sh = tid >> 5;           // s-subchunk (16 rows each)
        const int d0 = dg * 8;
        float dxv[8], dyv[8], sacc[8];
#pragma unroll
        for (int j = 0; j < 8; ++j) {
            dxv[j] = sdx[d0 + j];
            dyv[j] = sdy[d0 + j];
            sacc[j] = 0.f;
        }
        const int r0 = sc * 128 + sh * 16;
        const size_t base = ((size_t)b * 1024 + r0) * 256 + d0;
#pragma unroll 4
        for (int i = 0; i < 16; ++i) {
            const int4 v = *(const int4*)(XY8 + base + (size_t)i * 256);
            const int wv[4] = {v.x, v.y, v.z, v.w};
#pragma unroll
            for (int w = 0; w < 4; ++w) {
                f32x2 pa = __builtin_amdgcn_cvt_pk_f32_fp8(wv[w], false);
                f32x2 pb = __builtin_amdgcn_cvt_pk_f32_fp8(wv[w], true);
                float xa = pa[0] + dxv[2 * w],     ya = pa[1] + dyv[2 * w];
                float xb = pb[0] + dxv[2 * w + 1], yb = pb[1] + dyv[2 * w + 1];
                sacc[2 * w]     += sqrtf(xa * xa + ya * ya + EPS);
                sacc[2 * w + 1] += sqrtf(xb * xb + yb * yb + EPS);
            }
        }
#pragma unroll
        for (int j = 0; j < 8; ++j) red[tid][j] = sacc[j];
        __syncthreads();
        if (tid < 32) {
#pragma unroll
            for (int j = 0; j < 8; ++j) {
                float t = 0.f;
#pragma unroll
                for (int c = 0; c < 8; ++c) t += red[c * 32 + tid][j];
                atomicAdd(&pooled[b * 256 + tid * 8 + j], t);
            }
        }
    }
    __syncthreads();

    // ---- C) last block per b runs the classifier ----
    if (tid == 0) {
        __threadfence();                                   // release our adds
        unsigned old = __hip_atomic_fetch_add(&cnt[b], 1u, __ATOMIC_ACQ_REL,
                                              __HIP_MEMORY_SCOPE_AGENT);
        last_flag = (old == 7u);
    }
    __syncthreads();
    if (!last_flag) return;
    __threadfence();                                       // acquire side

    // atomic loads bypass L1 -> see all blocks' atomicAdds
    pl[tid] = __hip_atomic_load(&pooled[b * 256 + tid], __ATOMIC_RELAXED,
                                __HIP_MEMORY_SCOPE_AGENT) * (1.0f / 1024.0f);
    __syncthreads();
    const int hu = tid & 31, kc = tid >> 5;
    float a = 0.f;
    for (int k = kc * 32; k < kc * 32 + 32; ++k) a += pl[k] * cw1[k * 32 + hu];
    part[kc][hu] = a;
    __syncthreads();
    if (tid < 32) {
        float s2 = cb1[tid];
#pragma unroll
        for (int c = 0; c < 8; ++c) s2 += part[c][tid];
        hd[tid] = gelu_exact(s2);
    }
    __syncthreads();
    for (int n = tid; n < 1000; n += 256) {
        float s2 = cb2[n];
#pragma unroll
        for (int k = 0; k < 32; ++k) s2 += hd[k] * cw2[k * 1000 + n];
        out[b * 1000 + n] = s2;
    }
}

// ---------------------------------------------------------------------------
extern "C" void kernel_launch(void* const* d_in, const int* in_sizes, int n_in,
                              void* d_out, int out_size, void* d_ws, size_t ws_size,
                              hipStream_t stream)
{
    const float* x       = (const float*)d_in[0];
    const float* embed_w = (const float*)d_in[1];
    const float* embed_b = (const float*)d_in[2];
    const float* mag_w1  = (const float*)d_in[3];
    const float* mag_b1  = (const float*)d_in[4];
    const float* mag_w2  = (const float*)d_in[5];
    const float* mag_b2  = (const float*)d_in[6];
    const float* ph_w1   = (const float*)d_in[7];
    const float* ph_b1   = (const float*)d_in[8];
    const float* ph_w2   = (const float*)d_in[9];
    const float* ph_b2   = (const float*)d_in[10];
    const float* cls_w1  = (const float*)d_in[11];
    const float* cls_b1  = (const float*)d_in[12];
    const float* cls_w2  = (const float*)d_in[13];
    const float* cls_b2  = (const float*)d_in[14];
    float* out = (float*)d_out;

    char* ws = (char*)d_ws;
    unsigned short* XY8 = (unsigned short*)(ws + 0);   // 33554432 B (fp8 pairs)
    _Float16* Wth = (_Float16*)(ws + 33554432);        // 262144
    _Float16* Wtl = (_Float16*)(ws + 33816576);        // 262144
    float* XMsum  = (float*)(ws + 34078720);           // 65536
    float* YMsum  = (float*)(ws + 34144256);           // 65536
    float* pooled = (float*)(ws + 34209792);           // 65536
    unsigned* cnt = (unsigned*)(ws + 34275328);        // 256 (64 counters)

    // zero_base = XMsum: convertW zeros 49216 floats = XMsum,YMsum,pooled,cnt
    convertW<<<512, 256, 0, stream>>>(embed_w, Wth, Wtl, XMsum);
    gemm_embed<<<2048, 256, 0, stream>>>(x, Wth, Wtl, embed_b, XY8, XMsum, YMsum);
    tail_kernel<<<512, 256, 0, stream>>>(XY8, XMsum, YMsum,
                                         mag_w1, mag_b1, mag_w2, mag_b2,
                                         ph_w1, ph_b1, ph_w2, ph_b2,
                                         cls_w1, cls_b1, cls_w2, cls_b2,
                                         pooled, cnt, out);
}